// Round 3
// baseline (1026.315 us; speedup 1.0000x reference)
//
#include <hip/hip_runtime.h>

// GATv2 x2 layers. N=100000 nodes, E=1.6M edges (+N self loops).
// Pipeline: detect edge dtype -> build CSR by dst -> GEMM xl/xr -> per-node
// aggregate (attention softmax + weighted sum) -> relu -> layer 2 -> d_out.

#define NEG_SLOPE 0.2f

// ---------------- CSR build ----------------

__global__ __launch_bounds__(256) void k_zero_flag(int* flag) {
  if (threadIdx.x == 0 && blockIdx.x == 0) *flag = 0;
}

// If edge_index is int64, every high 32-bit word is 0 (values in [0,1e5)).
// If int32, odd int32 slots hold real node ids; 4096 consecutive zeros is impossible.
__global__ __launch_bounds__(256) void k_detect(const int* __restrict__ e32, int* flag, int cnt) {
  int i = blockIdx.x * 256 + threadIdx.x;
  if (i < cnt && e32[2 * i + 1] != 0) atomicOr(flag, 1);
}

__global__ __launch_bounds__(256) void k_initdeg(int* deg, int n) {
  int i = blockIdx.x * 256 + threadIdx.x;
  if (i < n) deg[i] = 1;  // self loop
}

__global__ __launch_bounds__(256) void k_countdeg(const int* __restrict__ e32,
                                                  const int* __restrict__ flag,
                                                  int* deg, int E) {
  int i = blockIdx.x * 256 + threadIdx.x;
  if (i >= E) return;
  int is32 = *flag;
  int d = is32 ? e32[E + i] : e32[2 * (E + i)];
  atomicAdd(&deg[d], 1);
}

__global__ __launch_bounds__(1024) void k_scan1(const int* __restrict__ deg,
                                                int* __restrict__ outv,
                                                int* __restrict__ bsums, int n) {
  __shared__ int tmp[1024];
  int tid = threadIdx.x;
  int i = blockIdx.x * 1024 + tid;
  int v = (i < n) ? deg[i] : 0;
  tmp[tid] = v;
  __syncthreads();
  for (int off = 1; off < 1024; off <<= 1) {
    int t = (tid >= off) ? tmp[tid - off] : 0;
    __syncthreads();
    tmp[tid] += t;
    __syncthreads();
  }
  if (i < n) outv[i] = tmp[tid] - v;  // exclusive (local)
  if (tid == 1023) bsums[blockIdx.x] = tmp[tid];
}

__global__ __launch_bounds__(1024) void k_scan2(int* bsums, int nb) {
  __shared__ int tmp[1024];
  int tid = threadIdx.x;
  int v = (tid < nb) ? bsums[tid] : 0;
  tmp[tid] = v;
  __syncthreads();
  for (int off = 1; off < 1024; off <<= 1) {
    int t = (tid >= off) ? tmp[tid - off] : 0;
    __syncthreads();
    tmp[tid] += t;
    __syncthreads();
  }
  if (tid < nb) bsums[tid] = tmp[tid] - v;  // exclusive
}

__global__ __launch_bounds__(1024) void k_scan3(int* rowptr, const int* __restrict__ bsums,
                                                int n, int E) {
  int i = blockIdx.x * 1024 + threadIdx.x;
  if (i < n) rowptr[i] += bsums[blockIdx.x];
  if (i == 0) rowptr[n] = n + E;  // total slots known statically
}

__global__ __launch_bounds__(256) void k_cursor_init(const int* __restrict__ rowptr,
                                                     int* __restrict__ colarr,
                                                     int* __restrict__ cursor, int n) {
  int i = blockIdx.x * 256 + threadIdx.x;
  if (i < n) {
    int p = rowptr[i];
    colarr[p] = i;       // self loop first
    cursor[i] = p + 1;
  }
}

__global__ __launch_bounds__(256) void k_fillcsr(const int* __restrict__ e32,
                                                 const int* __restrict__ flag,
                                                 int* __restrict__ cursor,
                                                 int* __restrict__ colarr, int E) {
  int i = blockIdx.x * 256 + threadIdx.x;
  if (i >= E) return;
  int is32 = *flag;
  int s = is32 ? e32[i] : e32[2 * i];
  int d = is32 ? e32[E + i] : e32[2 * (E + i)];
  int p = atomicAdd(&cursor[d], 1);
  colarr[p] = s;
}

// ---------------- GEMM: Y[n][COUT] = X[n][128] @ W[128][COUT] ----------------
// Tile: 48 rows x 64 cols per 256-thread block, K=128 fully staged in LDS.

template <int COUT>
__global__ __launch_bounds__(256) void k_gemm(const float* __restrict__ X,
                                              const float* __restrict__ W,
                                              float* __restrict__ Y, int nrows) {
  __shared__ float xs[48 * 132];   // padded stride 132 (2-way max conflict)
  __shared__ float wsh[128 * 64];
  int tid = threadIdx.x;
  int rbase = blockIdx.x * 48;
  int cbase = blockIdx.y * 64;

  // load W tile: 8192 floats = 2048 float4 / 256 threads
#pragma unroll
  for (int j = 0; j < 8; j++) {
    int flat = (tid + j * 256) * 4;
    int k = flat >> 6;
    int c = flat & 63;
    *(float4*)&wsh[k * 64 + c] = *(const float4*)&W[k * COUT + cbase + c];
  }
  // load X tile: 6144 floats = 1536 float4 / 256 threads
#pragma unroll
  for (int j = 0; j < 6; j++) {
    int flat = (tid + j * 256) * 4;
    int r = flat >> 7;
    int k = flat & 127;
    int gr = rbase + r;
    if (gr < nrows) *(float4*)&xs[r * 132 + k] = *(const float4*)&X[gr * 128 + k];
  }
  __syncthreads();

  int tc = tid & 15, tr = tid >> 4;
  int r0 = tr * 3, c0 = tc * 4;
  float acc[3][4] = {};

  for (int k0 = 0; k0 < 128; k0 += 4) {
    float xv[3][4], wv[4][4];
#pragma unroll
    for (int i = 0; i < 3; i++) {
      float4 t = *(float4*)&xs[(r0 + i) * 132 + k0];
      xv[i][0] = t.x; xv[i][1] = t.y; xv[i][2] = t.z; xv[i][3] = t.w;
    }
#pragma unroll
    for (int kk = 0; kk < 4; kk++) {
      float4 t = *(float4*)&wsh[(k0 + kk) * 64 + c0];
      wv[kk][0] = t.x; wv[kk][1] = t.y; wv[kk][2] = t.z; wv[kk][3] = t.w;
    }
#pragma unroll
    for (int i = 0; i < 3; i++)
#pragma unroll
      for (int kk = 0; kk < 4; kk++)
#pragma unroll
        for (int j = 0; j < 4; j++) acc[i][j] += xv[i][kk] * wv[kk][j];
  }

#pragma unroll
  for (int i = 0; i < 3; i++) {
    int gr = rbase + r0 + i;
    if (gr < nrows) {
      float4 o;
      o.x = acc[i][0]; o.y = acc[i][1]; o.z = acc[i][2]; o.w = acc[i][3];
      *(float4*)&Y[(size_t)gr * COUT + cbase + c0] = o;
    }
  }
}

// ---------------- GATv2 aggregate (wave per dst node) ----------------
// loop1: e_p = att . leakyrelu(xl[src]+xr[i]) (wave reduce), track max
// loop2: alpha = exp(e-m); out = sum alpha*xl[src] / sum alpha + bias

template <int C, bool RELU>
__global__ __launch_bounds__(256) void k_aggregate(
    const float* __restrict__ xl, const float* __restrict__ xr,
    const float* __restrict__ att, const float* __restrict__ bias,
    const int* __restrict__ rowptr, const int* __restrict__ col,
    float* __restrict__ out, int n) {
  constexpr int V = C / 64;
  __shared__ float eLDS[4][1024];
  int lane = threadIdx.x & 63;
  int wid = threadIdx.x >> 6;
  int node = blockIdx.x * 4 + wid;
  if (node >= n) return;

  int p0 = rowptr[node];
  int deg = rowptr[node + 1] - p0;
  if (deg > 1024) deg = 1024;  // never triggers (max deg ~50)

  float xrv[V], attv[V];
#pragma unroll
  for (int v = 0; v < V; v++) {
    xrv[v] = xr[(size_t)node * C + v * 64 + lane];
    attv[v] = att[v * 64 + lane];
  }

  float m = -1e30f;
  for (int p = 0; p < deg; p++) {
    int s = col[p0 + p];
    const float* xb = xl + (size_t)s * C;
    float e = 0.f;
#pragma unroll
    for (int v = 0; v < V; v++) {
      float t = xb[v * 64 + lane] + xrv[v];
      t = t > 0.f ? t : NEG_SLOPE * t;
      e += attv[v] * t;
    }
#pragma unroll
    for (int off = 32; off; off >>= 1) e += __shfl_xor(e, off, 64);
    if (lane == 0) eLDS[wid][p] = e;
    m = fmaxf(m, e);  // e uniform across lanes after butterfly
  }

  float denom = 0.f;
  float acc[V];
#pragma unroll
  for (int v = 0; v < V; v++) acc[v] = 0.f;
  for (int p = 0; p < deg; p++) {
    float al = __expf(eLDS[wid][p] - m);
    denom += al;
    int s = col[p0 + p];
    const float* xb = xl + (size_t)s * C;
#pragma unroll
    for (int v = 0; v < V; v++) acc[v] += al * xb[v * 64 + lane];
  }
  float inv = 1.f / denom;
#pragma unroll
  for (int v = 0; v < V; v++) {
    float o = acc[v] * inv + bias[v * 64 + lane];
    if (RELU) o = fmaxf(o, 0.f);
    out[(size_t)node * C + v * 64 + lane] = o;
  }
}

// ---------------- host ----------------

static inline char* bump(char*& p, size_t bytes) {
  char* r = p;
  p += (bytes + 255) & ~(size_t)255;
  return r;
}

extern "C" void kernel_launch(void* const* d_in, const int* in_sizes, int n_in,
                              void* d_out, int out_size, void* d_ws, size_t ws_size,
                              hipStream_t stream) {
  const float* x   = (const float*)d_in[0];
  const int* e32   = (const int*)d_in[1];
  const float* Wl1 = (const float*)d_in[2];
  const float* Wr1 = (const float*)d_in[3];
  const float* att1= (const float*)d_in[4];
  const float* b1  = (const float*)d_in[5];
  const float* Wl2 = (const float*)d_in[6];
  const float* Wr2 = (const float*)d_in[7];
  const float* att2= (const float*)d_in[8];
  const float* b2  = (const float*)d_in[9];

  const int N = in_sizes[0] / 128;
  const int E = in_sizes[1] / 2;

  char* p = (char*)d_ws;
  float* xl    = (float*)bump(p, (size_t)N * 128 * 4);
  float* xr    = (float*)bump(p, (size_t)N * 128 * 4);
  float* h     = (float*)bump(p, (size_t)N * 128 * 4);
  int* rowptr  = (int*)bump(p, (size_t)(N + 1) * 4);
  int* colarr  = (int*)bump(p, (size_t)(E + N) * 4);
  int* deg     = (int*)bump(p, (size_t)N * 4);  // reused as cursor
  int* bsums   = (int*)bump(p, 4096);
  int* flag    = (int*)bump(p, 256);

  // ---- CSR build ----
  k_zero_flag<<<1, 256, 0, stream>>>(flag);
  k_detect<<<16, 256, 0, stream>>>(e32, flag, 4096);
  k_initdeg<<<(N + 255) / 256, 256, 0, stream>>>(deg, N);
  k_countdeg<<<(E + 255) / 256, 256, 0, stream>>>(e32, flag, deg, E);
  int NB = (N + 1023) / 1024;
  k_scan1<<<NB, 1024, 0, stream>>>(deg, rowptr, bsums, N);
  k_scan2<<<1, 1024, 0, stream>>>(bsums, NB);
  k_scan3<<<NB, 1024, 0, stream>>>(rowptr, bsums, N, E);
  k_cursor_init<<<(N + 255) / 256, 256, 0, stream>>>(rowptr, colarr, deg, N);
  k_fillcsr<<<(E + 255) / 256, 256, 0, stream>>>(e32, flag, deg, colarr, E);

  // ---- layer 1 ----
  dim3 g1((N + 47) / 48, 2);
  k_gemm<128><<<g1, 256, 0, stream>>>(x, Wl1, xl, N);
  k_gemm<128><<<g1, 256, 0, stream>>>(x, Wr1, xr, N);
  k_aggregate<128, true><<<(N + 3) / 4, 256, 0, stream>>>(xl, xr, att1, b1, rowptr, colarr, h, N);

  // ---- layer 2 ----
  dim3 g2((N + 47) / 48, 1);
  k_gemm<64><<<g2, 256, 0, stream>>>(h, Wl2, xl, N);
  k_gemm<64><<<g2, 256, 0, stream>>>(h, Wr2, xr, N);
  k_aggregate<64, false><<<(N + 3) / 4, 256, 0, stream>>>(xl, xr, att2, b2, rowptr, colarr,
                                                          (float*)d_out, N);
}

// Round 6
// 688.011 us; speedup vs baseline: 1.4917x; 1.4917x over previous
//
#include <hip/hip_runtime.h>

// GATv2 x2 layers. N=100000 nodes, E=1.6M edges (+N self loops).
// Pipeline: detect edge dtype -> build CSR by dst -> GEMM xl/xr -> per-node
// single-pass online-softmax aggregate (4 edges/iter, 16 lanes/edge) -> d_out.

#define NEG_SLOPE 0.2f

// ---------------- CSR build ----------------

__global__ __launch_bounds__(256) void k_zero_flag(int* flag) {
  if (threadIdx.x == 0 && blockIdx.x == 0) *flag = 0;
}

// If edge_index is int64, every high 32-bit word is 0 (values in [0,1e5)).
// If int32, odd int32 slots hold real node ids; 4096 consecutive zeros is impossible.
__global__ __launch_bounds__(256) void k_detect(const int* __restrict__ e32, int* flag, int cnt) {
  int i = blockIdx.x * 256 + threadIdx.x;
  if (i < cnt && e32[2 * i + 1] != 0) atomicOr(flag, 1);
}

__global__ __launch_bounds__(256) void k_initdeg(int* deg, int n) {
  int i = blockIdx.x * 256 + threadIdx.x;
  if (i < n) deg[i] = 1;  // self loop
}

__global__ __launch_bounds__(256) void k_countdeg(const int* __restrict__ e32,
                                                  const int* __restrict__ flag,
                                                  int* deg, int E) {
  int i = blockIdx.x * 256 + threadIdx.x;
  if (i >= E) return;
  int is32 = *flag;
  int d = is32 ? e32[E + i] : e32[2 * (E + i)];
  atomicAdd(&deg[d], 1);
}

__global__ __launch_bounds__(1024) void k_scan1(const int* __restrict__ deg,
                                                int* __restrict__ outv,
                                                int* __restrict__ bsums, int n) {
  __shared__ int tmp[1024];
  int tid = threadIdx.x;
  int i = blockIdx.x * 1024 + tid;
  int v = (i < n) ? deg[i] : 0;
  tmp[tid] = v;
  __syncthreads();
  for (int off = 1; off < 1024; off <<= 1) {
    int t = (tid >= off) ? tmp[tid - off] : 0;
    __syncthreads();
    tmp[tid] += t;
    __syncthreads();
  }
  if (i < n) outv[i] = tmp[tid] - v;  // exclusive (local)
  if (tid == 1023) bsums[blockIdx.x] = tmp[tid];
}

__global__ __launch_bounds__(1024) void k_scan2(int* bsums, int nb) {
  __shared__ int tmp[1024];
  int tid = threadIdx.x;
  int v = (tid < nb) ? bsums[tid] : 0;
  tmp[tid] = v;
  __syncthreads();
  for (int off = 1; off < 1024; off <<= 1) {
    int t = (tid >= off) ? tmp[tid - off] : 0;
    __syncthreads();
    tmp[tid] += t;
    __syncthreads();
  }
  if (tid < nb) bsums[tid] = tmp[tid] - v;  // exclusive
}

__global__ __launch_bounds__(1024) void k_scan3(int* rowptr, const int* __restrict__ bsums,
                                                int n, int E) {
  int i = blockIdx.x * 1024 + threadIdx.x;
  if (i < n) rowptr[i] += bsums[blockIdx.x];
  if (i == 0) rowptr[n] = n + E;  // total slots known statically
}

__global__ __launch_bounds__(256) void k_cursor_init(const int* __restrict__ rowptr,
                                                     int* __restrict__ colarr,
                                                     int* __restrict__ cursor, int n) {
  int i = blockIdx.x * 256 + threadIdx.x;
  if (i < n) {
    int p = rowptr[i];
    colarr[p] = i;       // self loop first
    cursor[i] = p + 1;
  }
}

__global__ __launch_bounds__(256) void k_fillcsr(const int* __restrict__ e32,
                                                 const int* __restrict__ flag,
                                                 int* __restrict__ cursor,
                                                 int* __restrict__ colarr, int E) {
  int i = blockIdx.x * 256 + threadIdx.x;
  if (i >= E) return;
  int is32 = *flag;
  int s = is32 ? e32[i] : e32[2 * i];
  int d = is32 ? e32[E + i] : e32[2 * (E + i)];
  int p = atomicAdd(&cursor[d], 1);
  colarr[p] = s;
}

// ---------------- GEMM: Y[n][COUT] = X[n][128] @ W[128][COUT] ----------------
// Tile: 48 rows x 64 cols per 256-thread block, K=128 fully staged in LDS.

template <int COUT>
__global__ __launch_bounds__(256) void k_gemm(const float* __restrict__ X,
                                              const float* __restrict__ W,
                                              float* __restrict__ Y, int nrows) {
  __shared__ float xs[48 * 132];   // padded stride 132 (2-way max conflict)
  __shared__ float wsh[128 * 64];
  int tid = threadIdx.x;
  int rbase = blockIdx.x * 48;
  int cbase = blockIdx.y * 64;

  // load W tile: 8192 floats = 2048 float4 / 256 threads
#pragma unroll
  for (int j = 0; j < 8; j++) {
    int flat = (tid + j * 256) * 4;
    int k = flat >> 6;
    int c = flat & 63;
    *(float4*)&wsh[k * 64 + c] = *(const float4*)&W[k * COUT + cbase + c];
  }
  // load X tile: 6144 floats = 1536 float4 / 256 threads
#pragma unroll
  for (int j = 0; j < 6; j++) {
    int flat = (tid + j * 256) * 4;
    int r = flat >> 7;
    int k = flat & 127;
    int gr = rbase + r;
    if (gr < nrows) *(float4*)&xs[r * 132 + k] = *(const float4*)&X[gr * 128 + k];
  }
  __syncthreads();

  int tc = tid & 15, tr = tid >> 4;
  int r0 = tr * 3, c0 = tc * 4;
  float acc[3][4] = {};

  for (int k0 = 0; k0 < 128; k0 += 4) {
    float xv[3][4], wv[4][4];
#pragma unroll
    for (int i = 0; i < 3; i++) {
      float4 t = *(float4*)&xs[(r0 + i) * 132 + k0];
      xv[i][0] = t.x; xv[i][1] = t.y; xv[i][2] = t.z; xv[i][3] = t.w;
    }
#pragma unroll
    for (int kk = 0; kk < 4; kk++) {
      float4 t = *(float4*)&wsh[(k0 + kk) * 64 + c0];
      wv[kk][0] = t.x; wv[kk][1] = t.y; wv[kk][2] = t.z; wv[kk][3] = t.w;
    }
#pragma unroll
    for (int i = 0; i < 3; i++)
#pragma unroll
      for (int kk = 0; kk < 4; kk++)
#pragma unroll
        for (int j = 0; j < 4; j++) acc[i][j] += xv[i][kk] * wv[kk][j];
  }

#pragma unroll
  for (int i = 0; i < 3; i++) {
    int gr = rbase + r0 + i;
    if (gr < nrows) {
      float4 o;
      o.x = acc[i][0]; o.y = acc[i][1]; o.z = acc[i][2]; o.w = acc[i][3];
      *(float4*)&Y[(size_t)gr * COUT + cbase + c0] = o;
    }
  }
}

// ---------------- GATv2 aggregate: single-pass online softmax ----------------
// Wave per node. 4 edges per iteration: lane = (grp<<4)|ch; grp = edge
// sub-index, ch = channel block of V=C/16 channels. Each 16-lane group
// gathers one contiguous xl row (coalesced float4s), computes its edge's
// logit with a 4-step intra-group reduce, then the 4 logits are max-merged
// (2 cross-group shuffles) into the running online-softmax state. acc/denom
// are merged across groups once at the end. No LDS, no second gather pass.

template <int C, bool RELU>
__global__ __launch_bounds__(256) void k_aggregate(
    const float* __restrict__ xl, const float* __restrict__ xr,
    const float* __restrict__ att, const float* __restrict__ bias,
    const int* __restrict__ rowptr, const int* __restrict__ col,
    float* __restrict__ out, int n) {
  constexpr int V = C / 16;  // channels per lane (8 for C=128, 4 for C=64)
  int lane = threadIdx.x & 63;
  int wid = threadIdx.x >> 6;
  int node = blockIdx.x * 4 + wid;
  if (node >= n) return;
  int grp = lane >> 4;
  int ch = lane & 15;
  int c0 = ch * V;

  int p0 = rowptr[node];
  int deg = rowptr[node + 1] - p0;

  float xrv[V], attv[V], acc[V];
#pragma unroll
  for (int v = 0; v < V; v++) {
    xrv[v] = xr[(size_t)node * C + c0 + v];
    attv[v] = att[c0 + v];
    acc[v] = 0.f;
  }
  float m = -1e30f, denom = 0.f;

  for (int p = 0; p < deg; p += 4) {
    int pe = p + grp;
    bool valid = pe < deg;
    int s = col[p0 + (valid ? pe : 0)];
    const float* xb = xl + (size_t)s * C + c0;
    float xv[V];
#pragma unroll
    for (int v = 0; v < V; v += 4) {
      float4 t = *(const float4*)&xb[v];
      xv[v] = t.x; xv[v + 1] = t.y; xv[v + 2] = t.z; xv[v + 3] = t.w;
    }
    float e = 0.f;
#pragma unroll
    for (int v = 0; v < V; v++) {
      float t = xv[v] + xrv[v];
      t = t > 0.f ? t : NEG_SLOPE * t;
      e = fmaf(attv[v], t, e);
    }
    // intra-group (16-lane) sum -> e uniform within group
    e += __shfl_xor(e, 1);
    e += __shfl_xor(e, 2);
    e += __shfl_xor(e, 4);
    e += __shfl_xor(e, 8);
    if (!valid) e = -1e30f;
    // max over the 4 groups' logits (wave-uniform result)
    float mt = fmaxf(e, __shfl_xor(e, 16));
    mt = fmaxf(mt, __shfl_xor(mt, 32));
    float mn = fmaxf(m, mt);
    if (mn > m) {  // wave-uniform branch
      float r = __expf(m - mn);
      denom *= r;
#pragma unroll
      for (int v = 0; v < V; v++) acc[v] *= r;
      m = mn;
    }
    float al = __expf(e - m);  // 0 for invalid tail groups
    denom += al;
#pragma unroll
    for (int v = 0; v < V; v++) acc[v] = fmaf(al, xv[v], acc[v]);
  }

  // merge the 4 groups: denom (uniform within group) and acc per channel
  denom += __shfl_xor(denom, 16);
  denom += __shfl_xor(denom, 32);
#pragma unroll
  for (int v = 0; v < V; v++) {
    acc[v] += __shfl_xor(acc[v], 16);
    acc[v] += __shfl_xor(acc[v], 32);
  }

  if (lane < 16) {
    float inv = 1.f / denom;
#pragma unroll
    for (int v = 0; v < V; v += 4) {
      float4 o;
      o.x = acc[v] * inv + bias[c0 + v];
      o.y = acc[v + 1] * inv + bias[c0 + v + 1];
      o.z = acc[v + 2] * inv + bias[c0 + v + 2];
      o.w = acc[v + 3] * inv + bias[c0 + v + 3];
      if (RELU) {
        o.x = fmaxf(o.x, 0.f); o.y = fmaxf(o.y, 0.f);
        o.z = fmaxf(o.z, 0.f); o.w = fmaxf(o.w, 0.f);
      }
      *(float4*)&out[(size_t)node * C + c0 + v] = o;
    }
  }
}

// ---------------- host ----------------

static inline char* bump(char*& p, size_t bytes) {
  char* r = p;
  p += (bytes + 255) & ~(size_t)255;
  return r;
}

extern "C" void kernel_launch(void* const* d_in, const int* in_sizes, int n_in,
                              void* d_out, int out_size, void* d_ws, size_t ws_size,
                              hipStream_t stream) {
  const float* x   = (const float*)d_in[0];
  const int* e32   = (const int*)d_in[1];
  const float* Wl1 = (const float*)d_in[2];
  const float* Wr1 = (const float*)d_in[3];
  const float* att1= (const float*)d_in[4];
  const float* b1  = (const float*)d_in[5];
  const float* Wl2 = (const float*)d_in[6];
  const float* Wr2 = (const float*)d_in[7];
  const float* att2= (const float*)d_in[8];
  const float* b2  = (const float*)d_in[9];

  const int N = in_sizes[0] / 128;
  const int E = in_sizes[1] / 2;

  char* p = (char*)d_ws;
  float* xl    = (float*)bump(p, (size_t)N * 128 * 4);
  float* xr    = (float*)bump(p, (size_t)N * 128 * 4);
  float* h     = (float*)bump(p, (size_t)N * 128 * 4);
  int* rowptr  = (int*)bump(p, (size_t)(N + 1) * 4);
  int* colarr  = (int*)bump(p, (size_t)(E + N) * 4);
  int* deg     = (int*)bump(p, (size_t)N * 4);  // reused as cursor
  int* bsums   = (int*)bump(p, 4096);
  int* flag    = (int*)bump(p, 256);

  // ---- CSR build ----
  k_zero_flag<<<1, 256, 0, stream>>>(flag);
  k_detect<<<16, 256, 0, stream>>>(e32, flag, 4096);
  k_initdeg<<<(N + 255) / 256, 256, 0, stream>>>(deg, N);
  k_countdeg<<<(E + 255) / 256, 256, 0, stream>>>(e32, flag, deg, E);
  int NB = (N + 1023) / 1024;
  k_scan1<<<NB, 1024, 0, stream>>>(deg, rowptr, bsums, N);
  k_scan2<<<1, 1024, 0, stream>>>(bsums, NB);
  k_scan3<<<NB, 1024, 0, stream>>>(rowptr, bsums, N, E);
  k_cursor_init<<<(N + 255) / 256, 256, 0, stream>>>(rowptr, colarr, deg, N);
  k_fillcsr<<<(E + 255) / 256, 256, 0, stream>>>(e32, flag, deg, colarr, E);

  // ---- layer 1 ----
  dim3 g1((N + 47) / 48, 2);
  k_gemm<128><<<g1, 256, 0, stream>>>(x, Wl1, xl, N);
  k_gemm<128><<<g1, 256, 0, stream>>>(x, Wr1, xr, N);
  k_aggregate<128, true><<<(N + 3) / 4, 256, 0, stream>>>(xl, xr, att1, b1, rowptr, colarr, h, N);

  // ---- layer 2 ----
  dim3 g2((N + 47) / 48, 1);
  k_gemm<64><<<g2, 256, 0, stream>>>(h, Wl2, xl, N);
  k_gemm<64><<<g2, 256, 0, stream>>>(h, Wr2, xr, N);
  k_aggregate<64, false><<<(N + 3) / 4, 256, 0, stream>>>(xl, xr, att2, b2, rowptr, colarr,
                                                          (float*)d_out, N);
}

// Round 7
// 683.915 us; speedup vs baseline: 1.5006x; 1.0060x over previous
//
#include <hip/hip_runtime.h>

// GATv2 x2 layers. N=100000 nodes, E=1.6M edges (+N self loops).
// Pipeline: detect edge dtype -> build CSR by dst -> GEMM xl/xr -> per-node
// single-pass online-softmax aggregate (4 edges/iter, 16 lanes/edge,
// 2-deep software pipeline: col +2 iters, row +1 iter) -> d_out.

#define NEG_SLOPE 0.2f

// ---------------- CSR build ----------------

__global__ __launch_bounds__(256) void k_zero_flag(int* flag) {
  if (threadIdx.x == 0 && blockIdx.x == 0) *flag = 0;
}

// If edge_index is int64, every high 32-bit word is 0 (values in [0,1e5)).
// If int32, odd int32 slots hold real node ids; 4096 consecutive zeros is impossible.
__global__ __launch_bounds__(256) void k_detect(const int* __restrict__ e32, int* flag, int cnt) {
  int i = blockIdx.x * 256 + threadIdx.x;
  if (i < cnt && e32[2 * i + 1] != 0) atomicOr(flag, 1);
}

__global__ __launch_bounds__(256) void k_initdeg(int* deg, int n) {
  int i = blockIdx.x * 256 + threadIdx.x;
  if (i < n) deg[i] = 1;  // self loop
}

__global__ __launch_bounds__(256) void k_countdeg(const int* __restrict__ e32,
                                                  const int* __restrict__ flag,
                                                  int* deg, int E) {
  int i = blockIdx.x * 256 + threadIdx.x;
  if (i >= E) return;
  int is32 = *flag;
  int d = is32 ? e32[E + i] : e32[2 * (E + i)];
  atomicAdd(&deg[d], 1);
}

__global__ __launch_bounds__(1024) void k_scan1(const int* __restrict__ deg,
                                                int* __restrict__ outv,
                                                int* __restrict__ bsums, int n) {
  __shared__ int tmp[1024];
  int tid = threadIdx.x;
  int i = blockIdx.x * 1024 + tid;
  int v = (i < n) ? deg[i] : 0;
  tmp[tid] = v;
  __syncthreads();
  for (int off = 1; off < 1024; off <<= 1) {
    int t = (tid >= off) ? tmp[tid - off] : 0;
    __syncthreads();
    tmp[tid] += t;
    __syncthreads();
  }
  if (i < n) outv[i] = tmp[tid] - v;  // exclusive (local)
  if (tid == 1023) bsums[blockIdx.x] = tmp[tid];
}

__global__ __launch_bounds__(1024) void k_scan2(int* bsums, int nb) {
  __shared__ int tmp[1024];
  int tid = threadIdx.x;
  int v = (tid < nb) ? bsums[tid] : 0;
  tmp[tid] = v;
  __syncthreads();
  for (int off = 1; off < 1024; off <<= 1) {
    int t = (tid >= off) ? tmp[tid - off] : 0;
    __syncthreads();
    tmp[tid] += t;
    __syncthreads();
  }
  if (tid < nb) bsums[tid] = tmp[tid] - v;  // exclusive
}

__global__ __launch_bounds__(1024) void k_scan3(int* rowptr, const int* __restrict__ bsums,
                                                int n, int E) {
  int i = blockIdx.x * 1024 + threadIdx.x;
  if (i < n) rowptr[i] += bsums[blockIdx.x];
  if (i == 0) rowptr[n] = n + E;  // total slots known statically
}

__global__ __launch_bounds__(256) void k_cursor_init(const int* __restrict__ rowptr,
                                                     int* __restrict__ colarr,
                                                     int* __restrict__ cursor, int n) {
  int i = blockIdx.x * 256 + threadIdx.x;
  if (i < n) {
    int p = rowptr[i];
    colarr[p] = i;       // self loop first
    cursor[i] = p + 1;
  }
}

__global__ __launch_bounds__(256) void k_fillcsr(const int* __restrict__ e32,
                                                 const int* __restrict__ flag,
                                                 int* __restrict__ cursor,
                                                 int* __restrict__ colarr, int E) {
  int i = blockIdx.x * 256 + threadIdx.x;
  if (i >= E) return;
  int is32 = *flag;
  int s = is32 ? e32[i] : e32[2 * i];
  int d = is32 ? e32[E + i] : e32[2 * (E + i)];
  int p = atomicAdd(&cursor[d], 1);
  colarr[p] = s;
}

// ---------------- GEMM: Y[n][COUT] = X[n][128] @ W[128][COUT] ----------------
// Tile: 64 rows x 64 cols per 256-thread block (4x4 per thread), K=128 staged.
// 8 ds_read_b128 per 64 FMAs per thread per k-step; 65.8 KB LDS -> 2 blocks/CU.

template <int COUT>
__global__ __launch_bounds__(256) void k_gemm(const float* __restrict__ X,
                                              const float* __restrict__ W,
                                              float* __restrict__ Y, int nrows) {
  __shared__ float xs[64 * 132];   // padded stride 132
  __shared__ float wsh[128 * 64];
  int tid = threadIdx.x;
  int rbase = blockIdx.x * 64;
  int cbase = blockIdx.y * 64;

  // load W tile: 8192 floats = 2048 float4 / 256 threads
#pragma unroll
  for (int j = 0; j < 8; j++) {
    int flat = (tid + j * 256) * 4;
    int k = flat >> 6;
    int c = flat & 63;
    *(float4*)&wsh[k * 64 + c] = *(const float4*)&W[k * COUT + cbase + c];
  }
  // load X tile: 8192 floats = 2048 float4 / 256 threads
#pragma unroll
  for (int j = 0; j < 8; j++) {
    int flat = (tid + j * 256) * 4;
    int r = flat >> 7;
    int k = flat & 127;
    int gr = rbase + r;
    if (gr < nrows) *(float4*)&xs[r * 132 + k] = *(const float4*)&X[gr * 128 + k];
  }
  __syncthreads();

  int tc = tid & 15, tr = tid >> 4;
  int r0 = tr * 4, c0 = tc * 4;
  float acc[4][4] = {};

  for (int k0 = 0; k0 < 128; k0 += 4) {
    float xv[4][4], wv[4][4];
#pragma unroll
    for (int i = 0; i < 4; i++) {
      float4 t = *(float4*)&xs[(r0 + i) * 132 + k0];
      xv[i][0] = t.x; xv[i][1] = t.y; xv[i][2] = t.z; xv[i][3] = t.w;
    }
#pragma unroll
    for (int kk = 0; kk < 4; kk++) {
      float4 t = *(float4*)&wsh[(k0 + kk) * 64 + c0];
      wv[kk][0] = t.x; wv[kk][1] = t.y; wv[kk][2] = t.z; wv[kk][3] = t.w;
    }
#pragma unroll
    for (int i = 0; i < 4; i++)
#pragma unroll
      for (int kk = 0; kk < 4; kk++)
#pragma unroll
        for (int j = 0; j < 4; j++) acc[i][j] += xv[i][kk] * wv[kk][j];
  }

#pragma unroll
  for (int i = 0; i < 4; i++) {
    int gr = rbase + r0 + i;
    if (gr < nrows) {
      float4 o;
      o.x = acc[i][0]; o.y = acc[i][1]; o.z = acc[i][2]; o.w = acc[i][3];
      *(float4*)&Y[(size_t)gr * COUT + cbase + c0] = o;
    }
  }
}

// ---------------- GATv2 aggregate: single-pass online softmax ----------------
// Wave per node. 4 edges per iteration: lane = (grp<<4)|ch. Software pipeline:
// col index kept 2 iterations ahead, gathered row 1 iteration ahead, so the
// ~600-cycle random-row gather latency hides under the current iteration's
// shuffle-reduce/exp chain. Prefetch indices clamp to deg-1 (always valid;
// invalid contributions are zeroed via e=-1e30 after the reduce).

template <int C, bool RELU>
__global__ __launch_bounds__(256) void k_aggregate(
    const float* __restrict__ xl, const float* __restrict__ xr,
    const float* __restrict__ att, const float* __restrict__ bias,
    const int* __restrict__ rowptr, const int* __restrict__ col,
    float* __restrict__ out, int n) {
  constexpr int V = C / 16;  // channels per lane (8 for C=128, 4 for C=64)
  int lane = threadIdx.x & 63;
  int wid = threadIdx.x >> 6;
  int node = blockIdx.x * 4 + wid;
  if (node >= n) return;
  int grp = lane >> 4;
  int ch = lane & 15;
  int c0 = ch * V;

  int p0 = rowptr[node];
  int deg = rowptr[node + 1] - p0;
  int dm1 = deg - 1;

  float xrv[V], attv[V], acc[V];
#pragma unroll
  for (int v = 0; v < V; v++) {
    xrv[v] = xr[(size_t)node * C + c0 + v];
    attv[v] = att[c0 + v];
    acc[v] = 0.f;
  }
  float m = -1e30f, denom = 0.f;

  // pipeline prologue
  int i0 = grp < dm1 ? grp : dm1;
  int i1 = 4 + grp < dm1 ? 4 + grp : dm1;
  int sA = col[p0 + i0];
  int sB = col[p0 + i1];
  float xvA[V];
#pragma unroll
  for (int v = 0; v < V; v += 4) {
    float4 t = *(const float4*)&xl[(size_t)sA * C + c0 + v];
    xvA[v] = t.x; xvA[v + 1] = t.y; xvA[v + 2] = t.z; xvA[v + 3] = t.w;
  }

  for (int p = 0; p < deg; p += 4) {
    // issue next row gather (addr ready) and next-next col load
    float xvB[V];
#pragma unroll
    for (int v = 0; v < V; v += 4) {
      float4 t = *(const float4*)&xl[(size_t)sB * C + c0 + v];
      xvB[v] = t.x; xvB[v + 1] = t.y; xvB[v + 2] = t.z; xvB[v + 3] = t.w;
    }
    int i2 = p + 8 + grp < dm1 ? p + 8 + grp : dm1;
    int sC = col[p0 + i2];

    // compute on current row (xvA)
    bool valid = (p + grp) < deg;
    float e = 0.f;
#pragma unroll
    for (int v = 0; v < V; v++) {
      float t = xvA[v] + xrv[v];
      t = t > 0.f ? t : NEG_SLOPE * t;
      e = fmaf(attv[v], t, e);
    }
    e += __shfl_xor(e, 1);
    e += __shfl_xor(e, 2);
    e += __shfl_xor(e, 4);
    e += __shfl_xor(e, 8);
    if (!valid) e = -1e30f;
    float mt = fmaxf(e, __shfl_xor(e, 16));
    mt = fmaxf(mt, __shfl_xor(mt, 32));
    float mn = fmaxf(m, mt);
    if (mn > m) {  // wave-uniform branch
      float r = __expf(m - mn);
      denom *= r;
#pragma unroll
      for (int v = 0; v < V; v++) acc[v] *= r;
      m = mn;
    }
    float al = __expf(e - m);  // 0 for invalid tail groups
    denom += al;
#pragma unroll
    for (int v = 0; v < V; v++) acc[v] = fmaf(al, xvA[v], acc[v]);

    // rotate pipeline (waitcnt for xvB lands here, after the compute)
#pragma unroll
    for (int v = 0; v < V; v++) xvA[v] = xvB[v];
    sB = sC;
  }

  // merge the 4 groups: denom (uniform within group) and acc per channel
  denom += __shfl_xor(denom, 16);
  denom += __shfl_xor(denom, 32);
#pragma unroll
  for (int v = 0; v < V; v++) {
    acc[v] += __shfl_xor(acc[v], 16);
    acc[v] += __shfl_xor(acc[v], 32);
  }

  if (lane < 16) {
    float inv = 1.f / denom;
#pragma unroll
    for (int v = 0; v < V; v += 4) {
      float4 o;
      o.x = acc[v] * inv + bias[c0 + v];
      o.y = acc[v + 1] * inv + bias[c0 + v + 1];
      o.z = acc[v + 2] * inv + bias[c0 + v + 2];
      o.w = acc[v + 3] * inv + bias[c0 + v + 3];
      if (RELU) {
        o.x = fmaxf(o.x, 0.f); o.y = fmaxf(o.y, 0.f);
        o.z = fmaxf(o.z, 0.f); o.w = fmaxf(o.w, 0.f);
      }
      *(float4*)&out[(size_t)node * C + c0 + v] = o;
    }
  }
}

// ---------------- host ----------------

static inline char* bump(char*& p, size_t bytes) {
  char* r = p;
  p += (bytes + 255) & ~(size_t)255;
  return r;
}

extern "C" void kernel_launch(void* const* d_in, const int* in_sizes, int n_in,
                              void* d_out, int out_size, void* d_ws, size_t ws_size,
                              hipStream_t stream) {
  const float* x   = (const float*)d_in[0];
  const int* e32   = (const int*)d_in[1];
  const float* Wl1 = (const float*)d_in[2];
  const float* Wr1 = (const float*)d_in[3];
  const float* att1= (const float*)d_in[4];
  const float* b1  = (const float*)d_in[5];
  const float* Wl2 = (const float*)d_in[6];
  const float* Wr2 = (const float*)d_in[7];
  const float* att2= (const float*)d_in[8];
  const float* b2  = (const float*)d_in[9];

  const int N = in_sizes[0] / 128;
  const int E = in_sizes[1] / 2;

  char* p = (char*)d_ws;
  float* xl    = (float*)bump(p, (size_t)N * 128 * 4);
  float* xr    = (float*)bump(p, (size_t)N * 128 * 4);
  float* h     = (float*)bump(p, (size_t)N * 128 * 4);
  int* rowptr  = (int*)bump(p, (size_t)(N + 1) * 4);
  int* colarr  = (int*)bump(p, (size_t)(E + N) * 4);
  int* deg     = (int*)bump(p, (size_t)N * 4);  // reused as cursor
  int* bsums   = (int*)bump(p, 4096);
  int* flag    = (int*)bump(p, 256);

  // ---- CSR build ----
  k_zero_flag<<<1, 256, 0, stream>>>(flag);
  k_detect<<<16, 256, 0, stream>>>(e32, flag, 4096);
  k_initdeg<<<(N + 255) / 256, 256, 0, stream>>>(deg, N);
  k_countdeg<<<(E + 255) / 256, 256, 0, stream>>>(e32, flag, deg, E);
  int NB = (N + 1023) / 1024;
  k_scan1<<<NB, 1024, 0, stream>>>(deg, rowptr, bsums, N);
  k_scan2<<<1, 1024, 0, stream>>>(bsums, NB);
  k_scan3<<<NB, 1024, 0, stream>>>(rowptr, bsums, N, E);
  k_cursor_init<<<(N + 255) / 256, 256, 0, stream>>>(rowptr, colarr, deg, N);
  k_fillcsr<<<(E + 255) / 256, 256, 0, stream>>>(e32, flag, deg, colarr, E);

  // ---- layer 1 ----
  dim3 g1((N + 63) / 64, 2);
  k_gemm<128><<<g1, 256, 0, stream>>>(x, Wl1, xl, N);
  k_gemm<128><<<g1, 256, 0, stream>>>(x, Wr1, xr, N);
  k_aggregate<128, true><<<(N + 3) / 4, 256, 0, stream>>>(xl, xr, att1, b1, rowptr, colarr, h, N);

  // ---- layer 2 ----
  dim3 g2((N + 63) / 64, 1);
  k_gemm<64><<<g2, 256, 0, stream>>>(h, Wl2, xl, N);
  k_gemm<64><<<g2, 256, 0, stream>>>(h, Wr2, xr, N);
  k_aggregate<64, false><<<(N + 3) / 4, 256, 0, stream>>>(xl, xr, att2, b2, rowptr, colarr,
                                                          (float*)d_out, N);
}